// Round 13
// baseline (224.452 us; speedup 1.0000x reference)
//
#include <hip/hip_runtime.h>

#define DD 256
#define NH 8
#define HPT 2    // heads per thread
#define NHG 4    // head-groups (threads per row)

constexpr float LN_EPS = 1e-5f;
constexpr float SCALE  = 0.0625f;         // 1/sqrt(256)
// Scaled-Schraudolph, KS folded into per-head constants:
//   dh = (aq*KS)*x_j + (c*KS); NR-rcp(|dh|) = 2^23*log2e/|d_raw| is DIRECTLY
//   the exp bit-argument. sW accumulates RAW x_j.
constexpr float KS     = 8.2629579e-8f;   // ln2 / 2^23
constexpr float B_EXP  = 1064986816.0f;   // 2^23 * (127 - 0.0436775)
// T = 12 ln-units: truncation error <= 256*e^-12 ~ 1.6e-3 relative.
// T0 = 0.9375 * 12 * 12102203 (window inflated 6.7% to absorb NR rounding).
constexpr float T0     = 1.36150e8f;
#define RCP_MAGIC 0x7EF311C3u

// weight = bits-exp of (rcp|dh| - m), CLAMPED at B_EXP: any NR mis-ordering
// (r_j > m) collapses to the max weight 0.957 -- correct tie behavior -- and
// the inf-inf->NaN corner is absorbed (fminf returns the non-NaN operand).
// v_cvt_u32_f32 saturates neg/NaN -> 0 = exp underflow.
__device__ __forceinline__ float wexp_clamped(float dh, float Bh) {
    float y = __uint_as_float(RCP_MAGIC - __float_as_uint(dh));
    float w = fmaf(-fabsf(dh), fabsf(y), 2.0f);
    float f = fminf(fmaf(fabsf(y), w, Bh), B_EXP);
    unsigned u;
    asm("v_cvt_u32_f32 %0, %1" : "=v"(u) : "v"(f));
    return __uint_as_float(u);
}

// branchless search over 256 sorted floats; returns p in [0,255]; caller adds
// (a[p] < t) for the true lower_bound in [0,256].
__device__ __forceinline__ int lb256(const float* __restrict__ a, float t) {
    int p = 0;
    #pragma unroll
    for (int st = 128; st > 0; st >>= 1)
        p += (a[p + st - 1] < t) ? st : 0;
    return p;
}

// One (i,h) context, PER-LANE window over the sorted x (no wave vote):
//  - nearest-by-value neighbors of x* give dmin via the SAME fma/NR chain as
//    the scan (argmin element reproduces f == B_EXP -> sE >= 0.957, no 0/0)
//  - chunked float4 scan: DOWN from i1's chunk until chunk-min < vlo (argmin
//    chunk included by construction), then UP until chunk-min > max(vhi,x2)
//    (i2's chunk protected by the clamp). Dense lanes (mm<=0) get halfw=3e38
//    -> full-range scan; out-of-window elements underflow to 0 naturally.
__device__ __forceinline__ float2 fla_head(const float* __restrict__ xsrt,
                                           float aqk, float ck) {
    float inv_aqk = __builtin_amdgcn_rcpf(aqk);
    float xstar = fminf(fmaxf(-ck * inv_aqk, -1e5f), 1e5f);   // NaN/inf guard
    int pos = lb256(xsrt, xstar);
    pos += (xsrt[pos] < xstar) ? 1 : 0;       // true lower_bound in [0,256]
    int i1 = (pos - 1 > 0) ? pos - 1 : 0;
    int i2 = (pos < DD - 1) ? pos : DD - 1;
    float x2 = xsrt[i2];
    float d1 = fabsf(fmaf(aqk, xsrt[i1], ck));
    float d2 = fabsf(fmaf(aqk, x2, ck));
    float dm = fminf(d1, d2);
    float ym = __uint_as_float(RCP_MAGIC - __float_as_uint(dm));
    float m  = fabsf(ym) * fmaf(-dm, fabsf(ym), 2.0f);
    float Bh = B_EXP - m;
    float mm = fmaf(m, 0.9375f, -T0);         // >0 => truncation window valid
    float halfw = (mm > 0.f) ? __builtin_amdgcn_rcpf(mm) * fabsf(inv_aqk)
                             : 3e38f;
    float vlo = xstar - halfw;
    float vhi = fmaxf(xstar + halfw, x2);     // i2-chunk inclusion guarantee

    const float4* xs4 = reinterpret_cast<const float4*>(xsrt);
    float sE0=0.f,sE1=0.f,sE2=0.f,sE3=0.f;
    float sW0=0.f,sW1=0.f,sW2=0.f,sW3=0.f;
    const int c0 = i1 >> 2;
    // down-scan (accumulate first, then test: i1's chunk always included)
    for (int ci = c0; ci >= 0; --ci) {
        float4 xj = xs4[ci];
        float e0 = wexp_clamped(fmaf(aqk, xj.x, ck), Bh);
        float e1 = wexp_clamped(fmaf(aqk, xj.y, ck), Bh);
        float e2 = wexp_clamped(fmaf(aqk, xj.z, ck), Bh);
        float e3 = wexp_clamped(fmaf(aqk, xj.w, ck), Bh);
        sE0 += e0; sW0 = fmaf(e0, xj.x, sW0);
        sE1 += e1; sW1 = fmaf(e1, xj.y, sW1);
        sE2 += e2; sW2 = fmaf(e2, xj.z, sW2);
        sE3 += e3; sW3 = fmaf(e3, xj.w, sW3);
        if (xj.x < vlo) break;    // next chunk down is entirely below window
    }
    // up-scan
    for (int ci = c0 + 1; ci < DD/4; ++ci) {
        float4 xj = xs4[ci];
        if (xj.x > vhi) break;    // this & all further chunks above window
        float e0 = wexp_clamped(fmaf(aqk, xj.x, ck), Bh);
        float e1 = wexp_clamped(fmaf(aqk, xj.y, ck), Bh);
        float e2 = wexp_clamped(fmaf(aqk, xj.z, ck), Bh);
        float e3 = wexp_clamped(fmaf(aqk, xj.w, ck), Bh);
        sE0 += e0; sW0 = fmaf(e0, xj.x, sW0);
        sE1 += e1; sW1 = fmaf(e1, xj.y, sW1);
        sE2 += e2; sW2 = fmaf(e2, xj.z, sW2);
        sE3 += e3; sW3 = fmaf(e3, xj.w, sW3);
    }
    return make_float2((sE0+sE1)+(sE2+sE3), (sW0+sW1)+(sW2+sW3));
}

// Reduce two values across a 1024-thread block (16 waves). All threads get it.
__device__ __forceinline__ float2 block_reduce2(float a, float b, float* sc, int tid) {
    #pragma unroll
    for (int off = 32; off; off >>= 1) {
        a += __shfl_down(a, off, 64);
        b += __shfl_down(b, off, 64);
    }
    __syncthreads();                      // protect sc from previous use
    if ((tid & 63) == 0) { int w = tid >> 6; sc[w] = a; sc[16 + w] = b; }
    __syncthreads();
    const float4* s4 = reinterpret_cast<const float4*>(sc);
    float4 a0 = s4[0], a1 = s4[1], a2 = s4[2], a3 = s4[3];
    float4 b0 = s4[4], b1 = s4[5], b2 = s4[6], b3 = s4[7];
    float ra = ((a0.x+a0.y)+(a0.z+a0.w)) + ((a1.x+a1.y)+(a1.z+a1.w))
             + ((a2.x+a2.y)+(a2.z+a2.w)) + ((a3.x+a3.y)+(a3.z+a3.w));
    float rb = ((b0.x+b0.y)+(b0.z+b0.w)) + ((b1.x+b1.y)+(b1.z+b1.w))
             + ((b2.x+b2.y)+(b2.z+b2.w)) + ((b3.x+b3.y)+(b3.z+b3.w));
    return make_float2(ra, rb);
}

template<int LAST>
__global__ __launch_bounds__(1024, 8) void flann_layer(
    const float* __restrict__ x_in,     // [B, DD]
    const float* __restrict__ alphas,   // [NH, 3] this layer
    const float* __restrict__ betas,    // [NH, 3]
    const float* __restrict__ g1, const float* __restrict__ b1,   // fla LN
    const float* __restrict__ W,  const float* __restrict__ wb,   // [DD,DD], [DD]
    const float* __restrict__ g2, const float* __restrict__ b2,   // lin LN
    const float* __restrict__ outW, const float* __restrict__ outB,
    float* __restrict__ out)            // [B,DD] or [B] if LAST
{
    __shared__ __align__(16) float xsrt[DD];        // sorted x values
    __shared__ __align__(16) float xln[DD];
    __shared__ float comb[NHG][DD];                 // sort scratch, acc, GEMM
    __shared__ float sc[32];

    const int tid  = threadIdx.x;
    const int i    = tid & (DD - 1);    // feature row this thread owns
    const int hg   = tid >> 8;          // head-group 0..3 (heads 2hg, 2hg+1)
    const int bidx = blockIdx.x;

    const float* xrow = x_in + bidx * DD;
    float xv = xrow[i];                 // per-thread read (same across hg)

    // ---- register/shuffle bitonic sort of the 256 x values ----
    // All 1024 threads run it redundantly; j<64 steps are intra-wave
    // __shfl_xor (no barrier); j in {64,128} go through LDS.
    {
        float v = xv;
        float* flat = &comb[0][0];      // 1024-float scratch
        #pragma unroll
        for (int k = 2; k <= DD; k <<= 1) {
            #pragma unroll
            for (int j = k >> 1; j > 0; j >>= 1) {
                float p;
                if (j < 64) {
                    p = __shfl_xor(v, j, 64);
                } else {
                    flat[tid] = v;
                    __syncthreads();
                    p = flat[tid ^ j];
                    __syncthreads();
                }
                bool keepmin = (((i & j) == 0) == ((i & k) == 0));
                v = keepmin ? fminf(v, p) : fmaxf(v, p);
            }
        }
        if (hg == 0) xsrt[i] = v;
        __syncthreads();
    }

    // ---- my 2 heads' params (uniform -> SGPRs) ----
    const int h0 = hg * HPT;
    const float aq0 = alphas[h0*3+0], ak0 = alphas[h0*3+1], av0 = alphas[h0*3+2];
    const float bq0 = betas [h0*3+0], bk0 = betas [h0*3+1], bv0 = betas [h0*3+2];
    const float aq1 = alphas[h0*3+3], ak1 = alphas[h0*3+4], av1 = alphas[h0*3+5];
    const float bq1 = betas [h0*3+3], bk1 = betas [h0*3+4], bv1 = betas [h0*3+5];
    const float aqk0 = aq0 * KS, aqk1 = aq1 * KS;
    const float ck0  = (bq0 - fmaf(ak0, xv, bk0)) * KS;
    const float ck1  = (bq1 - fmaf(ak1, xv, bk1)) * KS;

    // ---- FLA: per-lane chunked window, one head at a time ----
    float2 s0 = fla_head(xsrt, aqk0, ck0);
    float2 s1 = fla_head(xsrt, aqk1, ck1);

    // sW in RAW x units -> no rescale. 1/sE via magic + 2 NR (~1e-6 rel).
    float yE0 = __uint_as_float(RCP_MAGIC - __float_as_uint(s0.x));
    float rE0 = fabsf(yE0) * fmaf(-s0.x, fabsf(yE0), 2.0f);
    rE0 = rE0 * fmaf(-s0.x, rE0, 2.0f);
    float yE1 = __uint_as_float(RCP_MAGIC - __float_as_uint(s1.x));
    float rE1 = fabsf(yE1) * fmaf(-s1.x, fabsf(yE1), 2.0f);
    rE1 = rE1 * fmaf(-s1.x, rE1, 2.0f);
    float accp = fmaf(av0, s0.y, bv0 * s0.x) * rE0
               + fmaf(av1, s1.y, bv1 * s1.x) * rE1;
    comb[hg][i] = accp;
    __syncthreads();

    // ---- combine head-groups, residual + ReLU (hg 0 only) ----
    float xr = 0.f;
    if (hg == 0) {
        float acc = (comb[0][i] + comb[1][i]) + (comb[2][i] + comb[3][i]);
        xr = fmaxf(fmaf(SCALE, acc, xv), 0.f);
    }

    // ---------------- LayerNorm 1 (hg!=0 contributes zeros) -----------------
    float2 r = block_reduce2(xr, xr * xr, sc, tid);
    float mu  = r.x * (1.f / DD);
    float var = r.y * (1.f / DD) - mu * mu;
    if (hg == 0) {
        float xn = (xr - mu) * __builtin_amdgcn_rsqf(var + LN_EPS);
        xln[i] = fmaf(xn, g1[i], b1[i]);
    }
    __syncthreads();

    // ---------------- Linear: d-range split 4 ways across hg ----------------
    const float4* xl4 = reinterpret_cast<const float4*>(xln);
    float ga0 = (hg == 0) ? wb[i] : 0.f, ga1 = 0.f, ga2 = 0.f, ga3 = 0.f;
    #pragma unroll 4
    for (int d4 = 0; d4 < DD/16; ++d4) {
        int g4 = hg * (DD/16) + d4;
        float4 xd = xl4[g4];
        int dr = 4 * g4;
        ga0 = fmaf(xd.x, W[(dr + 0) * DD + i], ga0);   // coalesced in i
        ga1 = fmaf(xd.y, W[(dr + 1) * DD + i], ga1);
        ga2 = fmaf(xd.z, W[(dr + 2) * DD + i], ga2);
        ga3 = fmaf(xd.w, W[(dr + 3) * DD + i], ga3);
    }
    comb[hg][i] = (ga0 + ga1) + (ga2 + ga3);
    __syncthreads();

    float gv = 0.f;
    if (hg == 0)
        gv = fmaxf((comb[0][i] + comb[1][i]) + (comb[2][i] + comb[3][i]), 0.f);

    // ---------------- LayerNorm 2 ----------------
    r = block_reduce2(gv, gv * gv, sc, tid);
    mu  = r.x * (1.f / DD);
    var = r.y * (1.f / DD) - mu * mu;
    float xo = 0.f;
    if (hg == 0)
        xo = fmaf((gv - mu) * __builtin_amdgcn_rsqf(var + LN_EPS), g2[i], b2[i]);

    if (!LAST) {
        if (hg == 0) out[bidx * DD + i] = xo;
    } else {
        float pr = (hg == 0) ? xo * outW[i] : 0.f;
        float2 p = block_reduce2(pr, 0.f, sc, tid);
        if (tid == 0) out[bidx] = p.x + outB[0];
    }
}

extern "C" void kernel_launch(void* const* d_in, const int* in_sizes, int n_in,
                              void* d_out, int out_size, void* d_ws, size_t ws_size,
                              hipStream_t stream) {
    const float* x      = (const float*)d_in[0];
    const float* alphas = (const float*)d_in[1];   // [L, NH, 3]
    const float* betas  = (const float*)d_in[2];   // [L, NH, 3]
    const float* flag   = (const float*)d_in[3];   // [L, DD]
    const float* flab   = (const float*)d_in[4];
    const float* linW   = (const float*)d_in[5];   // [L, DD, DD]
    const float* linb   = (const float*)d_in[6];   // [L, DD]
    const float* ling   = (const float*)d_in[7];
    const float* linb2  = (const float*)d_in[8];
    const float* outW   = (const float*)d_in[9];   // [DD]
    const float* outB   = (const float*)d_in[10];  // [1]

    const int B = in_sizes[0] / DD;
    float* ws   = (float*)d_ws;        // [B, DD] intermediate
    float* outp = (float*)d_out;       // [B]

    dim3 grid(B), block(1024);
    // layer 0: x -> ws
    flann_layer<0><<<grid, block, 0, stream>>>(
        x, alphas, betas, flag, flab, linW, linb, ling, linb2,
        nullptr, nullptr, ws);
    // layer 1 (+ fused final projection): ws -> out
    flann_layer<1><<<grid, block, 0, stream>>>(
        ws, alphas + NH*3, betas + NH*3, flag + DD, flab + DD,
        linW + DD*DD, linb + DD, ling + DD, linb2 + DD,
        outW, outB, outp);
}

// Round 14
// 158.019 us; speedup vs baseline: 1.4204x; 1.4204x over previous
//
#include <hip/hip_runtime.h>

#define DD 256
#define NH 8
#define HPT 2    // heads per thread
#define NHG 4    // head-groups (threads per row)

constexpr float LN_EPS = 1e-5f;
constexpr float SCALE  = 0.0625f;         // 1/sqrt(256)
// Scaled-Schraudolph, KS folded into per-head constants:
//   dh = (aq*KS)*x_j + (c*KS); NR-rcp(|dh|) = 2^23*log2e/|d_raw| is DIRECTLY
//   the exp bit-argument. sW accumulates RAW x_j.
constexpr float KS     = 8.2629579e-8f;   // ln2 / 2^23
constexpr float B_EXP  = 1064986816.0f;   // 2^23 * (127 - 0.0436775)
// T = 12 ln-units (validated R13: absmax 0.0078): err <= 256*e^-12 ~ 1.6e-3.
constexpr float T0     = 1.36150e8f;      // 0.9375 * 12 * 12102203
#define RCP_MAGIC 0x7EF311C3u

// weight = bits-exp of (rcp|dh| - m), CLAMPED at B_EXP (NR mis-order -> max
// weight = correct tie; NaN corner absorbed). cvt saturates neg/NaN -> 0.
__device__ __forceinline__ float wexp_clamped(float dh, float Bh) {
    float y = __uint_as_float(RCP_MAGIC - __float_as_uint(dh));
    float w = fmaf(-fabsf(dh), fabsf(y), 2.0f);
    float f = fminf(fmaf(fabsf(y), w, Bh), B_EXP);
    unsigned u;
    asm("v_cvt_u32_f32 %0, %1" : "=v"(u) : "v"(f));
    return __uint_as_float(u);
}

// branchless search over 256 sorted floats; returns p in [0,255]; caller adds
// (a[p] < t) for the true lower_bound in [0,256].
__device__ __forceinline__ int lb256(const float* __restrict__ a, float t) {
    int p = 0;
    #pragma unroll
    for (int st = 128; st > 0; st >>= 1)
        p += (a[p + st - 1] < t) ? st : 0;
    return p;
}

// order-preserving float<->uint32 mapping (total order = float order)
__device__ __forceinline__ unsigned f2s(float f) {
    unsigned u = __float_as_uint(f);
    return (u & 0x80000000u) ? ~u : (u | 0x80000000u);
}
__device__ __forceinline__ float s2f(unsigned s) {
    unsigned u = (s & 0x80000000u) ? (s ^ 0x80000000u) : ~s;
    return __uint_as_float(u);
}

// One (i,h) context: PRECOMPUTED per-lane chunk bounds (no in-loop break ->
// pipelined ds_read_b128). Argmin chunks included BY INDEX; out-of-window
// elements in boundary chunks underflow to ~0 harmlessly. Dense lanes
// (mm<=0) get the full range.
__device__ __forceinline__ float2 fla_head(const float* __restrict__ xsrt,
                                           float aqk, float ck) {
    float inv_aqk = __builtin_amdgcn_rcpf(aqk);
    float xstar = fminf(fmaxf(-ck * inv_aqk, -1e5f), 1e5f);   // NaN/inf guard
    int pos = lb256(xsrt, xstar);
    pos += (xsrt[pos] < xstar) ? 1 : 0;       // true lower_bound in [0,256]
    int i1 = (pos - 1 > 0) ? pos - 1 : 0;
    int i2 = (pos < DD - 1) ? pos : DD - 1;
    float x2 = xsrt[i2];
    float d1 = fabsf(fmaf(aqk, xsrt[i1], ck));
    float d2 = fabsf(fmaf(aqk, x2, ck));
    float dm = fminf(d1, d2);
    float ym = __uint_as_float(RCP_MAGIC - __float_as_uint(dm));
    float m  = fabsf(ym) * fmaf(-dm, fabsf(ym), 2.0f);
    float Bh = B_EXP - m;
    float mm = fmaf(m, 0.9375f, -T0);         // >0 => truncation window valid
    float halfw = (mm > 0.f) ? __builtin_amdgcn_rcpf(mm) * fabsf(inv_aqk)
                             : 3e38f;
    float vlo = xstar - halfw;
    float vhi = fmaxf(xstar + halfw, x2);
    int lo = lb256(xsrt, vlo); lo = (lo < i1) ? lo : i1;
    int hi = lb256(xsrt, vhi); hi += (xsrt[hi] < vhi) ? 1 : 0;
    hi = (hi > i2 + 1) ? hi : i2 + 1;

    const float4* xs4 = reinterpret_cast<const float4*>(xsrt);
    const int cLo = lo >> 2, cHi = (hi - 1) >> 2;
    float sE0=0.f,sE1=0.f,sE2=0.f,sE3=0.f;
    float sW0=0.f,sW1=0.f,sW2=0.f,sW3=0.f;
    #pragma unroll 2
    for (int ci = cLo; ci <= cHi; ++ci) {     // bounds precomputed: pipelines
        float4 xj = xs4[ci];
        float e0 = wexp_clamped(fmaf(aqk, xj.x, ck), Bh);
        float e1 = wexp_clamped(fmaf(aqk, xj.y, ck), Bh);
        float e2 = wexp_clamped(fmaf(aqk, xj.z, ck), Bh);
        float e3 = wexp_clamped(fmaf(aqk, xj.w, ck), Bh);
        sE0 += e0; sW0 = fmaf(e0, xj.x, sW0);
        sE1 += e1; sW1 = fmaf(e1, xj.y, sW1);
        sE2 += e2; sW2 = fmaf(e2, xj.z, sW2);
        sE3 += e3; sW3 = fmaf(e3, xj.w, sW3);
    }
    return make_float2((sE0+sE1)+(sE2+sE3), (sW0+sW1)+(sW2+sW3));
}

// Reduce two values across a 1024-thread block (16 waves). All threads get it.
__device__ __forceinline__ float2 block_reduce2(float a, float b, float* sc, int tid) {
    #pragma unroll
    for (int off = 32; off; off >>= 1) {
        a += __shfl_down(a, off, 64);
        b += __shfl_down(b, off, 64);
    }
    __syncthreads();                      // protect sc from previous use
    if ((tid & 63) == 0) { int w = tid >> 6; sc[w] = a; sc[16 + w] = b; }
    __syncthreads();
    const float4* s4 = reinterpret_cast<const float4*>(sc);
    float4 a0 = s4[0], a1 = s4[1], a2 = s4[2], a3 = s4[3];
    float4 b0 = s4[4], b1 = s4[5], b2 = s4[6], b3 = s4[7];
    float ra = ((a0.x+a0.y)+(a0.z+a0.w)) + ((a1.x+a1.y)+(a1.z+a1.w))
             + ((a2.x+a2.y)+(a2.z+a2.w)) + ((a3.x+a3.y)+(a3.z+a3.w));
    float rb = ((b0.x+b0.y)+(b0.z+b0.w)) + ((b1.x+b1.y)+(b1.z+b1.w))
             + ((b2.x+b2.y)+(b2.z+b2.w)) + ((b3.x+b3.y)+(b3.z+b3.w));
    return make_float2(ra, rb);
}

template<int LAST>
__global__ __launch_bounds__(1024, 8) void flann_layer(
    const float* __restrict__ x_in,     // [B, DD]
    const float* __restrict__ alphas,   // [NH, 3] this layer
    const float* __restrict__ betas,    // [NH, 3]
    const float* __restrict__ g1, const float* __restrict__ b1,   // fla LN
    const float* __restrict__ W,  const float* __restrict__ wb,   // [DD,DD], [DD]
    const float* __restrict__ g2, const float* __restrict__ b2,   // lin LN
    const float* __restrict__ outW, const float* __restrict__ outB,
    float* __restrict__ out)            // [B,DD] or [B] if LAST
{
    __shared__ __align__(16) float xsrt[DD];        // sorted x values
    __shared__ __align__(16) float xln[DD];
    __shared__ float comb[NHG][DD];                 // acc partials, then GEMM
    __shared__ float sc[32];
    __shared__ unsigned long long sflat[1024];      // 64-bit sort scratch

    const int tid  = threadIdx.x;
    const int i    = tid & (DD - 1);    // rank for FLA; orig row for epilogue
    const int hg   = tid >> 8;          // head-group 0..3 (heads 2hg, 2hg+1)
    const int bidx = blockIdx.x;

    const float* xrow = x_in + bidx * DD;
    float xv = xrow[i];                 // ORIGINAL-index value (epilogue)

    // ---- 64-bit key bitonic sort: (sortable(x) << 8) | orig_index ----
    // All 1024 threads run it redundantly; j<64 via __shfl_xor (no barrier),
    // j in {64,128} via LDS. Thread at lane i ends holding the rank-i key.
    float xr_v;  int idx_r;
    {
        unsigned long long v =
            ((unsigned long long)f2s(xv) << 8) | (unsigned)i;
        #pragma unroll
        for (int k = 2; k <= DD; k <<= 1) {
            #pragma unroll
            for (int j = k >> 1; j > 0; j >>= 1) {
                unsigned long long p;
                if (j < 64) {
                    p = __shfl_xor(v, j, 64);
                } else {
                    sflat[tid] = v;
                    __syncthreads();
                    p = sflat[tid ^ j];
                    __syncthreads();
                }
                bool keepmin = (((i & j) == 0) == ((i & k) == 0));
                v = keepmin ? (v < p ? v : p) : (v > p ? v : p);
            }
        }
        xr_v  = s2f((unsigned)(v >> 8));
        idx_r = (int)(v & 0xffu);
        if (hg == 0) xsrt[i] = xr_v;
        __syncthreads();
    }

    // ---- my 2 heads' params for the RANK-i context (value xr_v) ----
    // xstar is monotone in x, so adjacent lanes get adjacent windows:
    // max-over-lanes ~ mean, dense (tail) contexts cluster into few waves.
    const int h0 = hg * HPT;
    const float aq0 = alphas[h0*3+0], ak0 = alphas[h0*3+1], av0 = alphas[h0*3+2];
    const float bq0 = betas [h0*3+0], bk0 = betas [h0*3+1], bv0 = betas [h0*3+2];
    const float aq1 = alphas[h0*3+3], ak1 = alphas[h0*3+4], av1 = alphas[h0*3+5];
    const float bq1 = betas [h0*3+3], bk1 = betas [h0*3+4], bv1 = betas [h0*3+5];
    const float aqk0 = aq0 * KS, aqk1 = aq1 * KS;
    const float ck0  = (bq0 - fmaf(ak0, xr_v, bk0)) * KS;
    const float ck1  = (bq1 - fmaf(ak1, xr_v, bk1)) * KS;

    float2 s0 = fla_head(xsrt, aqk0, ck0);
    float2 s1 = fla_head(xsrt, aqk1, ck1);

    // sW in RAW x units -> no rescale. 1/sE via magic + 2 NR (~1e-6 rel).
    float yE0 = __uint_as_float(RCP_MAGIC - __float_as_uint(s0.x));
    float rE0 = fabsf(yE0) * fmaf(-s0.x, fabsf(yE0), 2.0f);
    rE0 = rE0 * fmaf(-s0.x, rE0, 2.0f);
    float yE1 = __uint_as_float(RCP_MAGIC - __float_as_uint(s1.x));
    float rE1 = fabsf(yE1) * fmaf(-s1.x, fabsf(yE1), 2.0f);
    rE1 = rE1 * fmaf(-s1.x, rE1, 2.0f);
    float accp = fmaf(av0, s0.y, bv0 * s0.x) * rE0
               + fmaf(av1, s1.y, bv1 * s1.x) * rE1;
    comb[hg][idx_r] = accp;             // scatter back to ORIGINAL index
    __syncthreads();

    // ---- combine head-groups, residual + ReLU (hg 0 only, original i) ----
    float xr = 0.f;
    if (hg == 0) {
        float acc = (comb[0][i] + comb[1][i]) + (comb[2][i] + comb[3][i]);
        xr = fmaxf(fmaf(SCALE, acc, xv), 0.f);
    }

    // ---------------- LayerNorm 1 (hg!=0 contributes zeros) -----------------
    float2 r = block_reduce2(xr, xr * xr, sc, tid);
    float mu  = r.x * (1.f / DD);
    float var = r.y * (1.f / DD) - mu * mu;
    if (hg == 0) {
        float xn = (xr - mu) * __builtin_amdgcn_rsqf(var + LN_EPS);
        xln[i] = fmaf(xn, g1[i], b1[i]);
    }
    __syncthreads();

    // ---------------- Linear: d-range split 4 ways across hg ----------------
    const float4* xl4 = reinterpret_cast<const float4*>(xln);
    float ga0 = (hg == 0) ? wb[i] : 0.f, ga1 = 0.f, ga2 = 0.f, ga3 = 0.f;
    #pragma unroll 4
    for (int d4 = 0; d4 < DD/16; ++d4) {
        int g4 = hg * (DD/16) + d4;
        float4 xd = xl4[g4];
        int dr = 4 * g4;
        ga0 = fmaf(xd.x, W[(dr + 0) * DD + i], ga0);   // coalesced in i
        ga1 = fmaf(xd.y, W[(dr + 1) * DD + i], ga1);
        ga2 = fmaf(xd.z, W[(dr + 2) * DD + i], ga2);
        ga3 = fmaf(xd.w, W[(dr + 3) * DD + i], ga3);
    }
    comb[hg][i] = (ga0 + ga1) + (ga2 + ga3);
    __syncthreads();

    float gv = 0.f;
    if (hg == 0)
        gv = fmaxf((comb[0][i] + comb[1][i]) + (comb[2][i] + comb[3][i]), 0.f);

    // ---------------- LayerNorm 2 ----------------
    r = block_reduce2(gv, gv * gv, sc, tid);
    mu  = r.x * (1.f / DD);
    var = r.y * (1.f / DD) - mu * mu;
    float xo = 0.f;
    if (hg == 0)
        xo = fmaf((gv - mu) * __builtin_amdgcn_rsqf(var + LN_EPS), g2[i], b2[i]);

    if (!LAST) {
        if (hg == 0) out[bidx * DD + i] = xo;
    } else {
        float pr = (hg == 0) ? xo * outW[i] : 0.f;
        float2 p = block_reduce2(pr, 0.f, sc, tid);
        if (tid == 0) out[bidx] = p.x + outB[0];
    }
}

extern "C" void kernel_launch(void* const* d_in, const int* in_sizes, int n_in,
                              void* d_out, int out_size, void* d_ws, size_t ws_size,
                              hipStream_t stream) {
    const float* x      = (const float*)d_in[0];
    const float* alphas = (const float*)d_in[1];   // [L, NH, 3]
    const float* betas  = (const float*)d_in[2];   // [L, NH, 3]
    const float* flag   = (const float*)d_in[3];   // [L, DD]
    const float* flab   = (const float*)d_in[4];
    const float* linW   = (const float*)d_in[5];   // [L, DD, DD]
    const float* linb   = (const float*)d_in[6];   // [L, DD]
    const float* ling   = (const float*)d_in[7];
    const float* linb2  = (const float*)d_in[8];
    const float* outW   = (const float*)d_in[9];   // [DD]
    const float* outB   = (const float*)d_in[10];  // [1]

    const int B = in_sizes[0] / DD;
    float* ws   = (float*)d_ws;        // [B, DD] intermediate
    float* outp = (float*)d_out;       // [B]

    dim3 grid(B), block(1024);
    // layer 0: x -> ws
    flann_layer<0><<<grid, block, 0, stream>>>(
        x, alphas, betas, flag, flab, linW, linb, ling, linb2,
        nullptr, nullptr, ws);
    // layer 1 (+ fused final projection): ws -> out
    flann_layer<1><<<grid, block, 0, stream>>>(
        ws, alphas + NH*3, betas + NH*3, flag + DD, flab + DD,
        linW + DD*DD, linb + DD, ling + DD, linb2 + DD,
        outW, outB, outp);
}

// Round 15
// 155.515 us; speedup vs baseline: 1.4433x; 1.0161x over previous
//
#include <hip/hip_runtime.h>

#define DD 256
#define NH 8
#define HPT 2    // heads per thread
#define NHG 4    // head-groups (threads per row)

constexpr float LN_EPS = 1e-5f;
constexpr float SCALE  = 0.0625f;         // 1/sqrt(256)
// Scaled-Schraudolph, KS folded into per-head constants:
//   dh = (aq*KS)*x_j + (c*KS); NR-rcp(|dh|) = 2^23*log2e/|d_raw| is DIRECTLY
//   the exp bit-argument. sW accumulates RAW x_j.
constexpr float KS     = 8.2629579e-8f;   // ln2 / 2^23
constexpr float B_EXP  = 1064986816.0f;   // 2^23 * (127 - 0.0436775)
// T = 12 ln-units (validated R13/R14: absmax 0.0078).
constexpr float T0     = 1.36150e8f;      // 0.9375 * 12 * 12102203
#define RCP_MAGIC 0x7EF311C3u

// weight = bits-exp of (rcp|dh| - m), CLAMPED at B_EXP (NR mis-order -> max
// weight = correct tie; NaN corner absorbed). cvt saturates neg/NaN -> 0.
__device__ __forceinline__ float wexp_clamped(float dh, float Bh) {
    float y = __uint_as_float(RCP_MAGIC - __float_as_uint(dh));
    float w = fmaf(-fabsf(dh), fabsf(y), 2.0f);
    float f = fminf(fmaf(fabsf(y), w, Bh), B_EXP);
    unsigned u;
    asm("v_cvt_u32_f32 %0, %1" : "=v"(u) : "v"(f));
    return __uint_as_float(u);
}

// branchless search over 256 near-sorted floats; returns p in [0,255].
__device__ __forceinline__ int lb256(const float* __restrict__ a, float t) {
    int p = 0;
    #pragma unroll
    for (int st = 128; st > 0; st >>= 1)
        p += (a[p + st - 1] < t) ? st : 0;
    return p;
}

// order-preserving float->uint32 (total order = float order)
__device__ __forceinline__ unsigned f2s(float f) {
    unsigned u = __float_as_uint(f);
    return (u & 0x80000000u) ? ~u : (u | 0x80000000u);
}

struct HeadCtx { float Bh; int cLo, cHi; };

// Window bounds for one (rank,head) context (R14-validated logic).
__device__ __forceinline__ HeadCtx fla_bounds(const float* __restrict__ xsrt,
                                              float aqk, float ck) {
    float inv_aqk = __builtin_amdgcn_rcpf(aqk);
    float xstar = fminf(fmaxf(-ck * inv_aqk, -1e5f), 1e5f);   // NaN/inf guard
    int pos = lb256(xsrt, xstar);
    pos += (xsrt[pos] < xstar) ? 1 : 0;
    int i1 = (pos - 1 > 0) ? pos - 1 : 0;
    int i2 = (pos < DD - 1) ? pos : DD - 1;
    float x2 = xsrt[i2];
    float d1 = fabsf(fmaf(aqk, xsrt[i1], ck));
    float d2 = fabsf(fmaf(aqk, x2, ck));
    float dm = fminf(d1, d2);
    float ym = __uint_as_float(RCP_MAGIC - __float_as_uint(dm));
    float m  = fabsf(ym) * fmaf(-dm, fabsf(ym), 2.0f);
    float mm = fmaf(m, 0.9375f, -T0);         // >0 => truncation window valid
    float halfw = (mm > 0.f) ? __builtin_amdgcn_rcpf(mm) * fabsf(inv_aqk)
                             : 3e38f;
    float vlo = xstar - halfw;
    float vhi = fmaxf(xstar + halfw, x2);
    int lo = lb256(xsrt, vlo); lo = (lo < i1) ? lo : i1;
    int hi = lb256(xsrt, vhi); hi += (xsrt[hi] < vhi) ? 1 : 0;
    hi = (hi > i2 + 1) ? hi : i2 + 1;
    HeadCtx h; h.Bh = B_EXP - m; h.cLo = lo >> 2; h.cHi = (hi - 1) >> 2;
    return h;
}

// Chunked scan with PRECOMPUTED bounds (pipelined ds_read_b128).
__device__ __forceinline__ float2 fla_scan(const float* __restrict__ xsrt,
                                           float aqk, float ck, HeadCtx hc) {
    const float4* xs4 = reinterpret_cast<const float4*>(xsrt);
    float sE0=0.f,sE1=0.f,sE2=0.f,sE3=0.f;
    float sW0=0.f,sW1=0.f,sW2=0.f,sW3=0.f;
    #pragma unroll 2
    for (int ci = hc.cLo; ci <= hc.cHi; ++ci) {
        float4 xj = xs4[ci];
        float e0 = wexp_clamped(fmaf(aqk, xj.x, ck), hc.Bh);
        float e1 = wexp_clamped(fmaf(aqk, xj.y, ck), hc.Bh);
        float e2 = wexp_clamped(fmaf(aqk, xj.z, ck), hc.Bh);
        float e3 = wexp_clamped(fmaf(aqk, xj.w, ck), hc.Bh);
        sE0 += e0; sW0 = fmaf(e0, xj.x, sW0);
        sE1 += e1; sW1 = fmaf(e1, xj.y, sW1);
        sE2 += e2; sW2 = fmaf(e2, xj.z, sW2);
        sE3 += e3; sW3 = fmaf(e3, xj.w, sW3);
    }
    return make_float2((sE0+sE1)+(sE2+sE3), (sW0+sW1)+(sW2+sW3));
}

// Reduce two values across a 1024-thread block (16 waves). All threads get it.
__device__ __forceinline__ float2 block_reduce2(float a, float b, float* sc, int tid) {
    #pragma unroll
    for (int off = 32; off; off >>= 1) {
        a += __shfl_down(a, off, 64);
        b += __shfl_down(b, off, 64);
    }
    __syncthreads();                      // protect sc from previous use
    if ((tid & 63) == 0) { int w = tid >> 6; sc[w] = a; sc[16 + w] = b; }
    __syncthreads();
    const float4* s4 = reinterpret_cast<const float4*>(sc);
    float4 a0 = s4[0], a1 = s4[1], a2 = s4[2], a3 = s4[3];
    float4 b0 = s4[4], b1 = s4[5], b2 = s4[6], b3 = s4[7];
    float ra = ((a0.x+a0.y)+(a0.z+a0.w)) + ((a1.x+a1.y)+(a1.z+a1.w))
             + ((a2.x+a2.y)+(a2.z+a2.w)) + ((a3.x+a3.y)+(a3.z+a3.w));
    float rb = ((b0.x+b0.y)+(b0.z+b0.w)) + ((b1.x+b1.y)+(b1.z+b1.w))
             + ((b2.x+b2.y)+(b2.z+b2.w)) + ((b3.x+b3.y)+(b3.z+b3.w));
    return make_float2(ra, rb);
}

template<int LAST>
__global__ __launch_bounds__(1024, 8) void flann_layer(
    const float* __restrict__ x_in,     // [B, DD]
    const float* __restrict__ alphas,   // [NH, 3] this layer
    const float* __restrict__ betas,    // [NH, 3]
    const float* __restrict__ g1, const float* __restrict__ b1,   // fla LN
    const float* __restrict__ W,  const float* __restrict__ wb,   // [DD,DD], [DD]
    const float* __restrict__ g2, const float* __restrict__ b2,   // lin LN
    const float* __restrict__ outW, const float* __restrict__ outB,
    float* __restrict__ out)            // [B,DD] or [B] if LAST
{
    __shared__ __align__(16) float xorig[DD];       // original-order values
    __shared__ __align__(16) float xsrt[DD];        // key-sorted exact values
    __shared__ __align__(16) float xln[DD];
    __shared__ unsigned karr[DD];                   // sorted 32-bit keys
    __shared__ float comb[NHG][DD];                 // sort scratch, acc, GEMM
    __shared__ float sc[32];

    const int tid  = threadIdx.x;
    const int i    = tid & (DD - 1);    // lane slot; orig row for epilogue
    const int hg   = tid >> 8;          // head-group 0..3 (heads 2hg, 2hg+1)
    const int bidx = blockIdx.x;

    const float* xrow = x_in + bidx * DD;
    float xv = xrow[i];                 // ORIGINAL-index value (epilogue)
    if (hg == 0) xorig[i] = xv;

    // ---- 32-bit key bitonic sort: (f2s(x) & ~0xFF) | orig_index ----
    // Truncating 8 mantissa bits only permutes near-equal values (<2^-16
    // rel) -> windows/argmin unaffected (index-clamped, inflated). All 1024
    // threads sort redundantly; j<64 via __shfl_xor, j in {64,128} via LDS.
    {
        unsigned v = (f2s(xv) & 0xFFFFFF00u) | (unsigned)i;
        unsigned* flat = reinterpret_cast<unsigned*>(&comb[0][0]);
        #pragma unroll
        for (int k = 2; k <= DD; k <<= 1) {
            #pragma unroll
            for (int j = k >> 1; j > 0; j >>= 1) {
                unsigned p;
                if (j < 64) {
                    p = (unsigned)__shfl_xor((int)v, j, 64);
                } else {
                    flat[tid] = v;
                    __syncthreads();
                    p = flat[tid ^ j];
                    __syncthreads();
                }
                bool keepmin = (((i & j) == 0) == ((i & k) == 0));
                v = keepmin ? (v < p ? v : p) : (v > p ? v : p);
            }
        }
        if (hg == 0) {                  // lane holds rank-i key
            karr[i] = v;
            xsrt[i] = xorig[v & 0xFFu]; // exact value, sorted order
        }
        __syncthreads();
    }

    // ---- tail-fold rank assignment: wave 0 of each hg takes BOTH tails ----
    // (dense = big-gap contexts live at extreme ranks; folding concentrates
    //  them into 1 of 4 waves instead of poisoning 2 of 4 with 64-chunk max)
    const int r     = (i & 1) ? (DD - 1) - (i >> 1) : (i >> 1);
    const unsigned kr = karr[r];
    const int idx_r = (int)(kr & 0xFFu);
    const float xr_v = xsrt[r];

    // ---- my 2 heads' params for the RANK-r context ----
    const int h0 = hg * HPT;
    const float aq0 = alphas[h0*3+0], ak0 = alphas[h0*3+1], av0 = alphas[h0*3+2];
    const float bq0 = betas [h0*3+0], bk0 = betas [h0*3+1], bv0 = betas [h0*3+2];
    const float aq1 = alphas[h0*3+3], ak1 = alphas[h0*3+4], av1 = alphas[h0*3+5];
    const float bq1 = betas [h0*3+3], bk1 = betas [h0*3+4], bv1 = betas [h0*3+5];
    const float aqk0 = aq0 * KS, aqk1 = aq1 * KS;
    const float ck0  = (bq0 - fmaf(ak0, xr_v, bk0)) * KS;
    const float ck1  = (bq1 - fmaf(ak1, xr_v, bk1)) * KS;

    // bounds for BOTH heads first (independent LDS chains interleave), then
    // both scans (precomputed bounds -> pipelined ds_read_b128)
    HeadCtx hc0 = fla_bounds(xsrt, aqk0, ck0);
    HeadCtx hc1 = fla_bounds(xsrt, aqk1, ck1);
    float2 s0 = fla_scan(xsrt, aqk0, ck0, hc0);
    float2 s1 = fla_scan(xsrt, aqk1, ck1, hc1);

    // sW in RAW x units -> no rescale. 1/sE via magic + 2 NR (~1e-6 rel).
    float yE0 = __uint_as_float(RCP_MAGIC - __float_as_uint(s0.x));
    float rE0 = fabsf(yE0) * fmaf(-s0.x, fabsf(yE0), 2.0f);
    rE0 = rE0 * fmaf(-s0.x, rE0, 2.0f);
    float yE1 = __uint_as_float(RCP_MAGIC - __float_as_uint(s1.x));
    float rE1 = fabsf(yE1) * fmaf(-s1.x, fabsf(yE1), 2.0f);
    rE1 = rE1 * fmaf(-s1.x, rE1, 2.0f);
    float accp = fmaf(av0, s0.y, bv0 * s0.x) * rE0
               + fmaf(av1, s1.y, bv1 * s1.x) * rE1;
    __syncthreads();                    // comb's sort-scratch use is done
    comb[hg][idx_r] = accp;             // scatter back to ORIGINAL index
    __syncthreads();

    // ---- combine head-groups, residual + ReLU (hg 0 only, original i) ----
    float xr = 0.f;
    if (hg == 0) {
        float acc = (comb[0][i] + comb[1][i]) + (comb[2][i] + comb[3][i]);
        xr = fmaxf(fmaf(SCALE, acc, xv), 0.f);
    }

    // ---------------- LayerNorm 1 (hg!=0 contributes zeros) -----------------
    float2 rr = block_reduce2(xr, xr * xr, sc, tid);
    float mu  = rr.x * (1.f / DD);
    float var = rr.y * (1.f / DD) - mu * mu;
    if (hg == 0) {
        float xn = (xr - mu) * __builtin_amdgcn_rsqf(var + LN_EPS);
        xln[i] = fmaf(xn, g1[i], b1[i]);
    }
    __syncthreads();

    // ---------------- Linear: d-range split 4 ways across hg ----------------
    const float4* xl4 = reinterpret_cast<const float4*>(xln);
    float ga0 = (hg == 0) ? wb[i] : 0.f, ga1 = 0.f, ga2 = 0.f, ga3 = 0.f;
    #pragma unroll 4
    for (int d4 = 0; d4 < DD/16; ++d4) {
        int g4 = hg * (DD/16) + d4;
        float4 xd = xl4[g4];
        int dr = 4 * g4;
        ga0 = fmaf(xd.x, W[(dr + 0) * DD + i], ga0);   // coalesced in i
        ga1 = fmaf(xd.y, W[(dr + 1) * DD + i], ga1);
        ga2 = fmaf(xd.z, W[(dr + 2) * DD + i], ga2);
        ga3 = fmaf(xd.w, W[(dr + 3) * DD + i], ga3);
    }
    comb[hg][i] = (ga0 + ga1) + (ga2 + ga3);
    __syncthreads();

    float gv = 0.f;
    if (hg == 0)
        gv = fmaxf((comb[0][i] + comb[1][i]) + (comb[2][i] + comb[3][i]), 0.f);

    // ---------------- LayerNorm 2 ----------------
    rr = block_reduce2(gv, gv * gv, sc, tid);
    mu  = rr.x * (1.f / DD);
    var = rr.y * (1.f / DD) - mu * mu;
    float xo = 0.f;
    if (hg == 0)
        xo = fmaf((gv - mu) * __builtin_amdgcn_rsqf(var + LN_EPS), g2[i], b2[i]);

    if (!LAST) {
        if (hg == 0) out[bidx * DD + i] = xo;
    } else {
        float pr = (hg == 0) ? xo * outW[i] : 0.f;
        float2 p = block_reduce2(pr, 0.f, sc, tid);
        if (tid == 0) out[bidx] = p.x + outB[0];
    }
}

extern "C" void kernel_launch(void* const* d_in, const int* in_sizes, int n_in,
                              void* d_out, int out_size, void* d_ws, size_t ws_size,
                              hipStream_t stream) {
    const float* x      = (const float*)d_in[0];
    const float* alphas = (const float*)d_in[1];   // [L, NH, 3]
    const float* betas  = (const float*)d_in[2];   // [L, NH, 3]
    const float* flag   = (const float*)d_in[3];   // [L, DD]
    const float* flab   = (const float*)d_in[4];
    const float* linW   = (const float*)d_in[5];   // [L, DD, DD]
    const float* linb   = (const float*)d_in[6];   // [L, DD]
    const float* ling   = (const float*)d_in[7];
    const float* linb2  = (const float*)d_in[8];
    const float* outW   = (const float*)d_in[9];   // [DD]
    const float* outB   = (const float*)d_in[10];  // [1]

    const int B = in_sizes[0] / DD;
    float* ws   = (float*)d_ws;        // [B, DD] intermediate
    float* outp = (float*)d_out;       // [B]

    dim3 grid(B), block(1024);
    // layer 0: x -> ws
    flann_layer<0><<<grid, block, 0, stream>>>(
        x, alphas, betas, flag, flab, linW, linb, ling, linb2,
        nullptr, nullptr, ws);
    // layer 1 (+ fused final projection): ws -> out
    flann_layer<1><<<grid, block, 0, stream>>>(
        ws, alphas + NH*3, betas + NH*3, flag + DD, flab + DD,
        linW + DD*DD, linb + DD, ling + DD, linb2 + DD,
        outW, outB, outp);
}